// Round 5
// baseline (414.733 us; speedup 1.0000x reference)
//
#include <hip/hip_runtime.h>
#include <stdint.h>

#define NB 64
#define CC 3
#define HH 12
#define WW 12
#define HW 144
#define KC 384
#define TINYF 1.17549435e-38f
// JAX >= 0.4.30 defaults jax_threefry_partitionable=True. In that mode,
// u32 random bits = XOR of the two threefry2x32 outputs on counter (0, e)
// (prng.py: convert_element_type(bits1 ^ bits2, u32)) — NOT the u64 truncation
// (= x1 alone) which round-4 shipped and which failed with absmax=126.
//   PARTITIONABLE=1 -> x0 ^ x1 (current best theory)
//   PARTITIONABLE=2 -> x1 only (tried round 4: FAILED absmax 126)
//   PARTITIONABLE=0 -> legacy split-iota halves (round-6 fallback)
#ifndef PARTITIONABLE
#define PARTITIONABLE 1
#endif

// Exact JAX threefry2x32 (20 rounds, key schedule per jax/_src/prng.py)
__device__ __forceinline__ void tf2x32(uint32_t k0, uint32_t k1,
                                       uint32_t& x0, uint32_t& x1) {
  const uint32_t ks2 = k0 ^ k1 ^ 0x1BD11BDAu;
  x0 += k0; x1 += k1;
#define RND(r) { x0 += x1; x1 = (x1 << (r)) | (x1 >> (32 - (r))); x1 ^= x0; }
  RND(13) RND(15) RND(26) RND(6)   x0 += k1;  x1 += ks2 + 1u;
  RND(17) RND(29) RND(16) RND(24)  x0 += ks2; x1 += k0 + 2u;
  RND(13) RND(15) RND(26) RND(6)   x0 += k0;  x1 += k1 + 3u;
  RND(17) RND(29) RND(16) RND(24)  x0 += k1;  x1 += ks2 + 4u;
  RND(13) RND(15) RND(26) RND(6)   x0 += ks2; x1 += k0 + 5u;
#undef RND
}

__device__ __forceinline__ uint32_t rbits(uint32_t k0, uint32_t k1, uint32_t e) {
#if PARTITIONABLE == 1
  uint32_t x0 = 0u, x1 = e;   // counter = (hi, lo) = (0, e)
  tf2x32(k0, k1, x0, x1);
  return x0 ^ x1;             // partitionable u32 bits = bits1 ^ bits2
#elif PARTITIONABLE == 2
  uint32_t x0 = 0u, x1 = e;
  tf2x32(k0, k1, x0, x1);
  return x1;                  // u64-truncation variant (refuted round 4)
#else
  const uint32_t half = (uint32_t)(NB * KC / 2);
  const bool lo = e < half;   // legacy: iota split in halves
  uint32_t x0 = lo ? e : e - half;
  uint32_t x1 = lo ? e + half : e;
  tf2x32(k0, k1, x0, x1);
  return lo ? x0 : x1;
#endif
}

__device__ __forceinline__ float gumbel32(uint32_t k0, uint32_t k1, uint32_t e) {
  const uint32_t bits = rbits(k0, k1, e);
  const float f = __uint_as_float((bits >> 9) | 0x3f800000u) - 1.0f;  // [0,1)
  const float u = fmaxf(TINYF, f + TINYF);   // == max(tiny, f*(1-tiny)+tiny) in f32
  return (float)(-log(-log((double)u)));     // correctly-rounded f32 gumbel
}

// Fully parallel gumbel precompute: gws[(n*HW + i)*KC + t]
__global__ __launch_bounds__(256) void gumbel_pre(float* __restrict__ gws) {
  const uint32_t tid = blockIdx.x * 256u + threadIdx.x;
  const uint32_t t  = tid % KC;
  const uint32_t ni = tid / KC;
  const uint32_t i  = ni % HW;
  const uint32_t n  = ni / HW;
  uint32_t a = 0u, b = i;          // fold_in(key(42), i) = threefry((0,42),(0,i))
  tf2x32(0u, 42u, a, b);
  gws[tid] = gumbel32(a, b, n * KC + t);
}

template<bool PRE>
__global__ __launch_bounds__(KC) void ar_sample(
    const float* __restrict__ cond,   // [N,C,H,W]
    const float* __restrict__ Wc,     // [K*C, C, 5, 5]
    const float* __restrict__ bias,   // [K*C]
    const float* __restrict__ gws,    // [N,HW,KC] gumbels (PRE path)
    float* __restrict__ out)          // [N,C,H,W]
{
  // channel-packed padded image: pixel (r,c) -> xp4[r+2][c+2] = (c0,c1,c2,pad)
  __shared__ float4   xp4[HH + 2][WW + 4];
  __shared__ float    valbuf[2][KC];    // double-buffered by step parity
  __shared__ float    cnd[CC * HW];
  __shared__ uint32_t keys0[HW], keys1[HW];   // !PRE path only

  const int n = blockIdx.x;     // one block per image
  const int t = threadIdx.x;    // t == k*C + c (output channel)
  const int lane = t & 63;

  // masked weights -> fp64 regs. taps 0..9 = rows 0,1 (shadow);
  // tap 10 = (2,0) reads pixel i-2; tap 11 = (2,1) reads pixel i-1 (registers)
  double wd[CC][12];
#pragma unroll
  for (int ci = 0; ci < CC; ++ci)
#pragma unroll
    for (int tap = 0; tap < 12; ++tap) {
      const int kh = tap < 10 ? tap / 5 : 2;
      const int kw = tap < 10 ? tap % 5 : tap - 10;
      wd[ci][tap] = (double)Wc[(t * CC + ci) * 25 + kh * 5 + kw];
    }
  const float bvf = bias[t];

  for (int idx = t; idx < (HH + 2) * (WW + 4); idx += KC)
    ((float4*)xp4)[idx] = make_float4(0.f, 0.f, 0.f, 0.f);
  for (int idx = t; idx < CC * HW; idx += KC)
    cnd[idx] = cond[n * CC * HW + idx];
  if (!PRE && t < HW) {
    uint32_t a = 0u, b = (uint32_t)t;
    tf2x32(0u, 42u, a, b);
    keys0[t] = a; keys1[t] = b;
  }
  __syncthreads();

  const uint32_t e = (uint32_t)(n * KC + t);  // flat index in [N,K,C] draw
  float g0 = 0.f, g1 = 0.f, g2 = 0.f;         // gumbel pipeline (depth 3 if PRE)
  if (PRE) {
    g0 = gws[(n * HW + 0) * KC + t];
    g1 = gws[(n * HW + 1) * KC + t];
    g2 = gws[(n * HW + 2) * KC + t];
  } else {
    g0 = gumbel32(keys0[0], keys1[0], e);
  }

  double part = 0.0;                            // rows-0/1 partial for pixel i
  float sA0=0.f,sA1=0.f,sA2=0.f;                // sampled pixel i-1 (all threads)
  float sB0=0.f,sB1=0.f,sB2=0.f;                // sampled pixel i-2

  for (int i = 0; i < HW; ++i) {
    const int h = i / WW, w = i - h * WW;

    // (A) complete pixel-i logits in registers, publish to this step's buffer.
    //     tap 11 (2,1) <- pixel i-1 (iff w>=1); tap 10 (2,0) <- pixel i-2 (iff
    //     w>=2); w-guards reproduce the SAME-conv zero left-pad exactly.
    double tot = part;
    if (w >= 1)
      tot += ((double)sA0 * wd[0][11] + (double)sA1 * wd[1][11])
           +  (double)sA2 * wd[2][11];
    if (w >= 2)
      tot += ((double)sB0 * wd[0][10] + (double)sB1 * wd[1][10])
           +  (double)sB2 * wd[2][10];
    valbuf[i & 1][t] = ((float)tot + bvf) + g0;  // f32 bias + f32 gumbel, XLA order

    __syncthreads();  // the ONLY barrier per step

    // (C) issue argmax input reads (2-way bank aliasing = free)
    const float* vb = valbuf[i & 1];
    float vlo[CC], vhi[CC];
#pragma unroll
    for (int c = 0; c < CC; ++c) {
      vlo[c] = vb[3 * lane + c];           // k = lane
      vhi[c] = vb[3 * lane + 192 + c];     // k = lane + 64
    }

    // (D) shadow under the val-read latency: rows-0/1 partial for pixel i+1.
    //     Reads only pixels <= i-9 (many barriers older than the write).
    double pn = 0.0; float gn = 0.f;
    if (i + 1 < HW) {
      const int i2 = i + 1, h2 = i2 / WW, w2 = i2 - h2 * WW;
      const float4* base = &xp4[h2][w2];   // tap (kh,kw) at base[kh*(WW+4)+kw]
      double a0=0,b0=0,a1=0,b1=0,a2=0,b2=0;
#pragma unroll
      for (int tap = 0; tap < 10; ++tap) {
        const int kh = tap / 5, kw = tap % 5;
        const float4 v = base[kh * (WW + 4) + kw];
        if (tap & 1) {
          b0 = fma((double)v.x, wd[0][tap], b0);
          b1 = fma((double)v.y, wd[1][tap], b1);
          b2 = fma((double)v.z, wd[2][tap], b2);
        } else {
          a0 = fma((double)v.x, wd[0][tap], a0);
          a1 = fma((double)v.y, wd[1][tap], a1);
          a2 = fma((double)v.z, wd[2][tap], a2);
        }
      }
      pn = (a0 + b0) + ((a1 + b1) + (a2 + b2));
      if (PRE) { if (i + 3 < HW) gn = gws[(n * HW + i + 3) * KC + t]; }
      else     { gn = gumbel32(keys0[i2], keys1[i2], e); }
    }

    // (E) redundant per-wave 3-channel argmax over k in [0,128);
    //     identical deterministic result in every wave; first-max-wins.
    float bm[CC]; int bi[CC];
#pragma unroll
    for (int c = 0; c < CC; ++c) {
      const bool hi = vhi[c] > vlo[c];
      bm[c] = hi ? vhi[c] : vlo[c];
      bi[c] = hi ? lane + 64 : lane;
    }
#pragma unroll
    for (int off = 32; off; off >>= 1) {
#pragma unroll
      for (int c = 0; c < CC; ++c) {
        const float ov = __shfl_xor(bm[c], off, 64);
        const int   oi = __shfl_xor(bi[c], off, 64);
        if (ov > bm[c] || (ov == bm[c] && oi < bi[c])) { bm[c] = ov; bi[c] = oi; }
      }
    }

    // (F) commit: registers in every thread; LDS/global writes from wave 0
    sB0 = sA0; sB1 = sA1; sB2 = sA2;
    const float c0 = cnd[0 * HW + i], c1 = cnd[1 * HW + i], c2 = cnd[2 * HW + i];
    sA0 = c0 < 0.f ? (float)bi[0] : c0;   // fill only unobserved (<0)
    sA1 = c1 < 0.f ? (float)bi[1] : c1;
    sA2 = c2 < 0.f ? (float)bi[2] : c2;
    if (t == 0) xp4[h + 2][w + 2] = make_float4(sA0, sA1, sA2, 0.f);
    if (t < CC) out[(n * CC + t) * HW + i] = t == 0 ? sA0 : (t == 1 ? sA1 : sA2);
    part = pn;
    if (PRE) { g0 = g1; g1 = g2; g2 = gn; } else { g0 = gn; }
  }
}

extern "C" void kernel_launch(void* const* d_in, const int* in_sizes, int n_in,
                              void* d_out, int out_size, void* d_ws, size_t ws_size,
                              hipStream_t stream) {
  const float* cond = (const float*)d_in[0];
  const float* Wc   = (const float*)d_in[1];
  const float* b    = (const float*)d_in[2];
  float* out = (float*)d_out;
  const size_t need = (size_t)NB * HW * KC * sizeof(float);  // 14.2 MB
  if (ws_size >= need) {
    float* gws = (float*)d_ws;
    hipLaunchKernelGGL(gumbel_pre, dim3((NB * HW * KC) / 256), dim3(256), 0,
                       stream, gws);
    hipLaunchKernelGGL((ar_sample<true>), dim3(NB), dim3(KC), 0, stream,
                       cond, Wc, b, gws, out);
  } else {
    hipLaunchKernelGGL((ar_sample<false>), dim3(NB), dim3(KC), 0, stream,
                       cond, Wc, b, (const float*)nullptr, out);
  }
}

// Round 7
// 172.348 us; speedup vs baseline: 2.4064x; 2.4064x over previous
//
#include <hip/hip_runtime.h>
#include <stdint.h>

#define NB 64
#define CC 3
#define HH 12
#define WW 12
#define HW 144
#define KC 384
#define TINYF 1.17549435e-38f
// VERIFIED round 5: partitionable RNG (x0^x1) + fp64 conv -> absmax 0.0
#ifndef PARTITIONABLE
#define PARTITIONABLE 1
#endif

// Exact JAX threefry2x32 (20 rounds, key schedule per jax/_src/prng.py)
__device__ __forceinline__ void tf2x32(uint32_t k0, uint32_t k1,
                                       uint32_t& x0, uint32_t& x1) {
  const uint32_t ks2 = k0 ^ k1 ^ 0x1BD11BDAu;
  x0 += k0; x1 += k1;
#define RND(r) { x0 += x1; x1 = (x1 << (r)) | (x1 >> (32 - (r))); x1 ^= x0; }
  RND(13) RND(15) RND(26) RND(6)   x0 += k1;  x1 += ks2 + 1u;
  RND(17) RND(29) RND(16) RND(24)  x0 += ks2; x1 += k0 + 2u;
  RND(13) RND(15) RND(26) RND(6)   x0 += k0;  x1 += k1 + 3u;
  RND(17) RND(29) RND(16) RND(24)  x0 += k1;  x1 += ks2 + 4u;
  RND(13) RND(15) RND(26) RND(6)   x0 += ks2; x1 += k0 + 5u;
#undef RND
}

__device__ __forceinline__ uint32_t rbits(uint32_t k0, uint32_t k1, uint32_t e) {
#if PARTITIONABLE == 1
  uint32_t x0 = 0u, x1 = e;   // counter (0, e); u32 bits = bits1 ^ bits2
  tf2x32(k0, k1, x0, x1);
  return x0 ^ x1;
#else
  const uint32_t half = (uint32_t)(NB * KC / 2);
  const bool lo = e < half;
  uint32_t x0 = lo ? e : e - half;
  uint32_t x1 = lo ? e + half : e;
  tf2x32(k0, k1, x0, x1);
  return lo ? x0 : x1;
#endif
}

__device__ __forceinline__ float gumbel32(uint32_t k0, uint32_t k1, uint32_t e) {
  const uint32_t bits = rbits(k0, k1, e);
  const float f = __uint_as_float((bits >> 9) | 0x3f800000u) - 1.0f;  // [0,1)
  const float u = fmaxf(TINYF, f + TINYF);
  return (float)(-log(-log((double)u)));
}

// Gumbel precompute, PERMUTED layout: gws[(n*HW+i)*KC + c*128 + k],
// value = gumbel(e = n*KC + k*3 + c)  (e = flat [N,K,C] draw index).
__global__ __launch_bounds__(256) void gumbel_pre(float* __restrict__ gws) {
  const uint32_t tid = blockIdx.x * 256u + threadIdx.x;
  const uint32_t t  = tid % KC;          // = c*128 + k
  const uint32_t c  = t >> 7, k = t & 127u;
  const uint32_t ni = tid / KC;
  const uint32_t i  = ni % HW;
  const uint32_t n  = ni / HW;
  uint32_t a = 0u, b = i;                // fold_in(key(42), i)
  tf2x32(0u, 42u, a, b);
  gws[tid] = gumbel32(a, b, n * KC + k * 3u + c);
}

// ---- DPP wave64 max-reduce (VALU-only, no DS pipe) ----
template<int CTRL>
__device__ __forceinline__ float dpp_max_step(float v) {
  const int o = __builtin_amdgcn_update_dpp(0xFF800000, __float_as_int(v),
                                            CTRL, 0xF, 0xF, false); // old=-inf
  return fmaxf(v, __int_as_float(o));
}
__device__ __forceinline__ float wave_max_bcast(float v) {
  v = dpp_max_step<0x111>(v);  // row_shr:1
  v = dpp_max_step<0x112>(v);  // row_shr:2
  v = dpp_max_step<0x114>(v);  // row_shr:4
  v = dpp_max_step<0x118>(v);  // row_shr:8
  v = dpp_max_step<0x142>(v);  // row_bcast:15
  v = dpp_max_step<0x143>(v);  // row_bcast:31
  return __int_as_float(__builtin_amdgcn_readlane(__float_as_int(v), 63));
}

// 3 waves/block: wave = output channel c; lane holds k = lane and k = lane+64.
template<bool PRE>
__global__ __launch_bounds__(192, 1) void ar_sample(
    const float* __restrict__ cond,   // [N,C,H,W]
    const float* __restrict__ Wc,     // [K*C, C, 5, 5]
    const float* __restrict__ bias,   // [K*C]
    const float* __restrict__ gws,    // [N,HW,C,K] gumbels (PRE)
    float* __restrict__ out)          // [N,C,H,W]
{
  __shared__ float4   xp4[HH + 2][WW + 4];  // padded image, channel-packed
  __shared__ float4   outb[HW];             // per-pixel samples; also exchange
  __shared__ float    cndl[CC * HW];
  __shared__ uint32_t k0s[HW], k1s[HW];     // !PRE only

  const int n    = blockIdx.x;
  const int t    = threadIdx.x;
  const int lane = t & 63;
  const int cw   = t >> 6;        // this wave's channel
  float* outf = (float*)outb;

  // ---- init: weights (fp64 regs), bias, LDS buffers ----
  double wdA[CC][12], wdB[CC][12];
#pragma unroll
  for (int ci = 0; ci < CC; ++ci)
#pragma unroll
    for (int tap = 0; tap < 12; ++tap) {
      const int kh = tap < 10 ? tap / 5 : 2;
      const int kw = tap < 10 ? tap % 5 : tap - 10;
      wdA[ci][tap] = (double)Wc[(lane * 3 + cw) * 75 + ci * 25 + kh * 5 + kw];
      wdB[ci][tap] = (double)Wc[((lane + 64) * 3 + cw) * 75 + ci * 25 + kh * 5 + kw];
    }
  const float bA = bias[lane * 3 + cw];
  const float bB = bias[(lane + 64) * 3 + cw];

  for (int idx = t; idx < (HH + 2) * (WW + 4); idx += 192)
    ((float4*)xp4)[idx] = make_float4(0.f, 0.f, 0.f, 0.f);
  for (int idx = t; idx < CC * HW; idx += 192)
    cndl[idx] = cond[n * CC * HW + idx];
  if (!PRE && t < HW) {
    uint32_t a = 0u, b = (uint32_t)t;
    tf2x32(0u, 42u, a, b);
    k0s[t] = a; k1s[t] = b;
  }
  __syncthreads();

  // gumbel register pipeline: current row (gA/gB) + in-flight next row (nAr/nBr)
  float gA[WW], gB[WW], nAr[WW], nBr[WW], cr[WW];
  if (PRE) {
#pragma unroll
    for (int w = 0; w < WW; ++w) {   // prologue: issue row 0
      nAr[w] = gws[(n * HW + w) * KC + cw * 128 + lane];
      nBr[w] = gws[(n * HW + w) * KC + cw * 128 + 64 + lane];
    }
  } else {
#pragma unroll
    for (int w = 0; w < WW; ++w) {
      nAr[w] = gumbel32(k0s[w], k1s[w], n * KC + lane * 3 + cw);
      nBr[w] = gumbel32(k0s[w], k1s[w], n * KC + (lane + 64) * 3 + cw);
    }
  }

  double partA = 0.0, partB = 0.0;          // rows-0/1 partials for pixel i
  float sA0 = 0.f, sA1 = 0.f, sA2 = 0.f;    // pixel i-1
  float sB0 = 0.f, sB1 = 0.f, sB2 = 0.f;    // pixel i-2

  for (int h = 0; h < HH; ++h) {
    // row top: consume in-flight gumbels (compiler inserts the vmcnt waits),
    // preload this row's cond, issue next row's gumbel loads.
#pragma unroll
    for (int w = 0; w < WW; ++w) { gA[w] = nAr[w]; gB[w] = nBr[w]; }
#pragma unroll
    for (int w = 0; w < WW; ++w) cr[w] = cndl[cw * HW + h * WW + w];
    if (h + 1 < HH) {
      if (PRE) {
#pragma unroll
        for (int w = 0; w < WW; ++w) {
          const int i2 = (h + 1) * WW + w;
          nAr[w] = gws[(n * HW + i2) * KC + cw * 128 + lane];
          nBr[w] = gws[(n * HW + i2) * KC + cw * 128 + 64 + lane];
        }
      } else {
#pragma unroll
        for (int w = 0; w < WW; ++w) {
          const int i2 = (h + 1) * WW + w;
          nAr[w] = gumbel32(k0s[i2], k1s[i2], n * KC + lane * 3 + cw);
          nBr[w] = gumbel32(k0s[i2], k1s[i2], n * KC + (lane + 64) * 3 + cw);
        }
      }
    }

#pragma unroll
    for (int w = 0; w < WW; ++w) {
      const int i = h * WW + w;

      // shadow reads for pixel i+1 (rows h2-2, h2-1: pixels <= i-7, i.e.
      // written >= 6 barriers before this pre-barrier read -> race-free)
      const int h2 = (w == WW - 1) ? h + 1 : h;
      const int w2 = (w == WW - 1) ? 0 : w + 1;
      float4 px[10];
#pragma unroll
      for (int tap = 0; tap < 10; ++tap)
        px[tap] = xp4[h2 + tap / 5][w2 + tap % 5];

      // completion of pixel-i logits (taps (2,1)<-pixel i-1, (2,0)<-pixel i-2;
      // w-guards reproduce the SAME-conv zero left-pad exactly)
      double tA = partA, tB = partB;
      if (w >= 1) {
        tA += ((double)sA0 * wdA[0][11] + (double)sA1 * wdA[1][11]) + (double)sA2 * wdA[2][11];
        tB += ((double)sA0 * wdB[0][11] + (double)sA1 * wdB[1][11]) + (double)sA2 * wdB[2][11];
      }
      if (w >= 2) {
        tA += ((double)sB0 * wdA[0][10] + (double)sB1 * wdA[1][10]) + (double)sB2 * wdA[2][10];
        tB += ((double)sB0 * wdB[0][10] + (double)sB1 * wdB[1][10]) + (double)sB2 * wdB[2][10];
      }
      const float vA = ((float)tA + bA) + gA[w];
      const float vB = ((float)tB + bB) + gB[w];

      // first-max-wins argmax over k in [0,128):
      // DPP max-reduce, then ballot-based min-index (k<64 candidates are the
      // vA's, k>=64 the vB's -> aMask wins ties exactly like jnp.argmax).
      const float vm   = fmaxf(vA, vB);
      const float smax = wave_max_bcast(vm);
      const unsigned long long aM = __ballot(vA == smax);
      const unsigned long long bM = __ballot(vB == smax);
      const int kwin = aM ? (int)__builtin_ctzll(aM)
                          : (int)__builtin_ctzll(bM) + 64;

      const float cv   = cr[w];
      const float sNew = (cv < 0.f) ? (float)kwin : cv;  // fill unobserved only
      if (lane == 0) outf[i * 4 + cw] = sNew;            // exchange + output

      // raw barrier: LDS-only ordering; vmcnt (gumbel prefetch) NOT drained
      asm volatile("s_waitcnt lgkmcnt(0)" ::: "memory");
      __builtin_amdgcn_s_barrier();
      __builtin_amdgcn_sched_barrier(0);

      const float4 ex = outb[i];    // all 3 channels of pixel i
      sB0 = sA0; sB1 = sA1; sB2 = sA2;
      sA0 = ex.x; sA1 = ex.y; sA2 = ex.z;
      if (t == 0) xp4[h + 2][w + 2] = make_float4(sA0, sA1, sA2, 0.f);

      // shadow FMAs overlap the ex-read latency (post-barrier issue)
      double pA0 = 0, pA1 = 0, pB0 = 0, pB1 = 0;
#pragma unroll
      for (int tap = 0; tap < 10; ++tap) {
        const float4 v = px[tap];
        if (tap & 1) {
          pA1 = fma((double)v.x, wdA[0][tap], pA1);
          pA1 = fma((double)v.y, wdA[1][tap], pA1);
          pA1 = fma((double)v.z, wdA[2][tap], pA1);
          pB1 = fma((double)v.x, wdB[0][tap], pB1);
          pB1 = fma((double)v.y, wdB[1][tap], pB1);
          pB1 = fma((double)v.z, wdB[2][tap], pB1);
        } else {
          pA0 = fma((double)v.x, wdA[0][tap], pA0);
          pA0 = fma((double)v.y, wdA[1][tap], pA0);
          pA0 = fma((double)v.z, wdA[2][tap], pA0);
          pB0 = fma((double)v.x, wdB[0][tap], pB0);
          pB0 = fma((double)v.y, wdB[1][tap], pB0);
          pB0 = fma((double)v.z, wdB[2][tap], pB0);
        }
      }
      partA = pA0 + pA1; partB = pB0 + pB1;
    }
  }

  __syncthreads();
  for (int idx = t; idx < CC * HW; idx += 192) {
    const int c = idx / HW, i = idx - c * HW;
    out[n * CC * HW + idx] = outf[i * 4 + c];
  }
}

extern "C" void kernel_launch(void* const* d_in, const int* in_sizes, int n_in,
                              void* d_out, int out_size, void* d_ws, size_t ws_size,
                              hipStream_t stream) {
  const float* cond = (const float*)d_in[0];
  const float* Wc   = (const float*)d_in[1];
  const float* b    = (const float*)d_in[2];
  float* out = (float*)d_out;
  const size_t need = (size_t)NB * HW * KC * sizeof(float);  // 14.2 MB
  if (ws_size >= need) {
    float* gws = (float*)d_ws;
    hipLaunchKernelGGL(gumbel_pre, dim3((NB * HW * KC) / 256), dim3(256), 0,
                       stream, gws);
    hipLaunchKernelGGL((ar_sample<true>), dim3(NB), dim3(192), 0, stream,
                       cond, Wc, b, gws, out);
  } else {
    hipLaunchKernelGGL((ar_sample<false>), dim3(NB), dim3(192), 0, stream,
                       cond, Wc, b, (const float*)nullptr, out);
  }
}

// Round 10
// 161.083 us; speedup vs baseline: 2.5747x; 1.0699x over previous
//
#include <hip/hip_runtime.h>
#include <stdint.h>

#define NB 64
#define CC 3
#define HH 12
#define WW 12
#define HW 144
#define KC 384
#define TINYF 1.17549435e-38f
// VERIFIED round 5/7: partitionable RNG (x0^x1) + fp64 conv -> absmax 0.0
#ifndef PARTITIONABLE
#define PARTITIONABLE 1
#endif

// Exact JAX threefry2x32 (20 rounds, key schedule per jax/_src/prng.py)
__device__ __forceinline__ void tf2x32(uint32_t k0, uint32_t k1,
                                       uint32_t& x0, uint32_t& x1) {
  const uint32_t ks2 = k0 ^ k1 ^ 0x1BD11BDAu;
  x0 += k0; x1 += k1;
#define RND(r) { x0 += x1; x1 = (x1 << (r)) | (x1 >> (32 - (r))); x1 ^= x0; }
  RND(13) RND(15) RND(26) RND(6)   x0 += k1;  x1 += ks2 + 1u;
  RND(17) RND(29) RND(16) RND(24)  x0 += ks2; x1 += k0 + 2u;
  RND(13) RND(15) RND(26) RND(6)   x0 += k0;  x1 += k1 + 3u;
  RND(17) RND(29) RND(16) RND(24)  x0 += k1;  x1 += ks2 + 4u;
  RND(13) RND(15) RND(26) RND(6)   x0 += ks2; x1 += k0 + 5u;
#undef RND
}

__device__ __forceinline__ uint32_t rbits(uint32_t k0, uint32_t k1, uint32_t e) {
#if PARTITIONABLE == 1
  uint32_t x0 = 0u, x1 = e;   // counter (0, e); u32 bits = bits1 ^ bits2
  tf2x32(k0, k1, x0, x1);
  return x0 ^ x1;
#else
  const uint32_t half = (uint32_t)(NB * KC / 2);
  const bool lo = e < half;
  uint32_t x0 = lo ? e : e - half;
  uint32_t x1 = lo ? e + half : e;
  tf2x32(k0, k1, x0, x1);
  return lo ? x0 : x1;
#endif
}

__device__ __forceinline__ float gumbel32(uint32_t k0, uint32_t k1, uint32_t e) {
  const uint32_t bits = rbits(k0, k1, e);
  const float f = __uint_as_float((bits >> 9) | 0x3f800000u) - 1.0f;  // [0,1)
  const float u = fmaxf(TINYF, f + TINYF);
  return (float)(-log(-log((double)u)));
}

// Gumbel precompute, PERMUTED layout: gws[(n*HW+i)*KC + c*128 + k],
// value = gumbel(e = n*KC + k*3 + c)  (e = flat [N,K,C] draw index).
__global__ __launch_bounds__(256) void gumbel_pre(float* __restrict__ gws) {
  const uint32_t tid = blockIdx.x * 256u + threadIdx.x;
  const uint32_t t  = tid % KC;          // = c*128 + k
  const uint32_t c  = t >> 7, k = t & 127u;
  const uint32_t ni = tid / KC;
  const uint32_t i  = ni % HW;
  const uint32_t n  = ni / HW;
  uint32_t a = 0u, b = i;                // fold_in(key(42), i)
  tf2x32(0u, 42u, a, b);
  gws[tid] = gumbel32(a, b, n * KC + k * 3u + c);
}

// ---- DPP wave64 max-reduce (VALU-only, no DS pipe) ----
template<int CTRL>
__device__ __forceinline__ float dpp_max_step(float v) {
  const int o = __builtin_amdgcn_update_dpp(0xFF800000, __float_as_int(v),
                                            CTRL, 0xF, 0xF, false); // old=-inf
  return fmaxf(v, __int_as_float(o));
}
__device__ __forceinline__ float wave_max_bcast(float v) {
  v = dpp_max_step<0x111>(v);  // row_shr:1
  v = dpp_max_step<0x112>(v);  // row_shr:2
  v = dpp_max_step<0x114>(v);  // row_shr:4
  v = dpp_max_step<0x118>(v);  // row_shr:8
  v = dpp_max_step<0x142>(v);  // row_bcast:15
  v = dpp_max_step<0x143>(v);  // row_bcast:31
  return __int_as_float(__builtin_amdgcn_readlane(__float_as_int(v), 63));
}

// 6 waves: waves 0-2 = SAMPLER (channel cw; completion+argmax+exchange);
// waves 3-5 = SHADOW (channel cw; rows-0/1 10-tap partial for pixel i+2,
// published into a 4-slot fp64 LDS ring). Shadow reads pixels <= i-8 only.
template<bool PRE>
__global__ __launch_bounds__(384, 1) void ar_sample(
    const float* __restrict__ cond,   // [N,C,H,W]
    const float* __restrict__ Wc,     // [K*C, C, 5, 5]
    const float* __restrict__ bias,   // [K*C]
    const float* __restrict__ gws,    // [N,HW,C,K] gumbels (PRE)
    float* __restrict__ out)          // [N,C,H,W]
{
  __shared__ float4   xp4[HH + 2][WW + 4];  // padded image, channel-packed
  __shared__ float4   outb[HW];             // per-pixel samples; also exchange
  __shared__ float    cndl[CC * HW];
  __shared__ double   pd[4][KC];            // partial ring: pd[j&3][c*128+k]
  __shared__ uint32_t k0s[HW], k1s[HW];     // !PRE only

  const int n    = blockIdx.x;
  const int t    = threadIdx.x;
  const int lane = t & 63;
  float* outf = (float*)outb;

  // ---- common setup ----
  for (int idx = t; idx < (HH + 2) * (WW + 4); idx += 384)
    ((float4*)xp4)[idx] = make_float4(0.f, 0.f, 0.f, 0.f);
  for (int idx = t; idx < CC * HW; idx += 384)
    cndl[idx] = cond[n * CC * HW + idx];
#pragma unroll
  for (int s = 0; s < 4; ++s) pd[s][t] = 0.0;   // t in [0,384) == KC
  if (!PRE && t < HW) {
    uint32_t a = 0u, b = (uint32_t)t;
    tf2x32(0u, 42u, a, b);
    k0s[t] = a; k1s[t] = b;
  }
  __syncthreads();

  if (t < 192) {
    // ================= SAMPLER =================
    const int cw = t >> 6;
    double wA10[3], wA11[3], wB10[3], wB11[3];  // taps (2,0),(2,1)
#pragma unroll
    for (int ci = 0; ci < 3; ++ci) {
      wA10[ci] = (double)Wc[(lane * 3 + cw) * 75 + ci * 25 + 10];
      wA11[ci] = (double)Wc[(lane * 3 + cw) * 75 + ci * 25 + 11];
      wB10[ci] = (double)Wc[((lane + 64) * 3 + cw) * 75 + ci * 25 + 10];
      wB11[ci] = (double)Wc[((lane + 64) * 3 + cw) * 75 + ci * 25 + 11];
    }
    const float bA = bias[lane * 3 + cw];
    const float bB = bias[(lane + 64) * 3 + cw];

    float gA[WW], gB[WW], nAr[WW], nBr[WW], cr[WW];
    if (PRE) {
#pragma unroll
      for (int w = 0; w < WW; ++w) {   // prologue: issue row 0
        nAr[w] = gws[(n * HW + w) * KC + cw * 128 + lane];
        nBr[w] = gws[(n * HW + w) * KC + cw * 128 + 64 + lane];
      }
    } else {
#pragma unroll
      for (int w = 0; w < WW; ++w) {
        nAr[w] = gumbel32(k0s[w], k1s[w], n * KC + lane * 3 + cw);
        nBr[w] = gumbel32(k0s[w], k1s[w], n * KC + (lane + 64) * 3 + cw);
      }
    }

    double pdAc = 0.0, pdBc = 0.0;   // partial for pixel i   (row 0 -> 0)
    double pdAn = 0.0, pdBn = 0.0;   // partial for pixel i+1 (row 0 -> 0)
    float sA0 = 0.f, sA1 = 0.f, sA2 = 0.f;   // pixel i-1
    float sB0 = 0.f, sB1 = 0.f, sB2 = 0.f;   // pixel i-2
    __builtin_amdgcn_s_setprio(1);

    for (int h = 0; h < HH; ++h) {
#pragma unroll
      for (int w = 0; w < WW; ++w) { gA[w] = nAr[w]; gB[w] = nBr[w]; }
#pragma unroll
      for (int w = 0; w < WW; ++w) cr[w] = cndl[cw * HW + h * WW + w];
      if (h + 1 < HH) {
        if (PRE) {
#pragma unroll
          for (int w = 0; w < WW; ++w) {
            const int i2 = (h + 1) * WW + w;
            nAr[w] = gws[(n * HW + i2) * KC + cw * 128 + lane];
            nBr[w] = gws[(n * HW + i2) * KC + cw * 128 + 64 + lane];
          }
        } else {
#pragma unroll
          for (int w = 0; w < WW; ++w) {
            const int i2 = (h + 1) * WW + w;
            nAr[w] = gumbel32(k0s[i2], k1s[i2], n * KC + lane * 3 + cw);
            nBr[w] = gumbel32(k0s[i2], k1s[i2], n * KC + (lane + 64) * 3 + cw);
          }
        }
      }

#pragma unroll
      for (int w = 0; w < WW; ++w) {
        const int i = h * WW + w;

        // completion: taps (2,1)<-pixel i-1, (2,0)<-pixel i-2 (registers);
        // w-guards reproduce the SAME-conv zero left-pad exactly.
        double tA = pdAc, tB = pdBc;
        if (w >= 1) {
          tA += ((double)sA0 * wA11[0] + (double)sA1 * wA11[1]) + (double)sA2 * wA11[2];
          tB += ((double)sA0 * wB11[0] + (double)sA1 * wB11[1]) + (double)sA2 * wB11[2];
        }
        if (w >= 2) {
          tA += ((double)sB0 * wA10[0] + (double)sB1 * wA10[1]) + (double)sB2 * wA10[2];
          tB += ((double)sB0 * wB10[0] + (double)sB1 * wB10[1]) + (double)sB2 * wB10[2];
        }
        const float vA = ((float)tA + bA) + gA[w];
        const float vB = ((float)tB + bB) + gB[w];

        // first-max-wins argmax over k in [0,128): DPP max + ballot min-index
        const float vm   = fmaxf(vA, vB);
        const float smax = wave_max_bcast(vm);
        const unsigned long long aM = __ballot(vA == smax);
        const unsigned long long bM = __ballot(vB == smax);
        const int kwin = aM ? (int)__builtin_ctzll(aM)
                            : (int)__builtin_ctzll(bM) + 64;

        const float cv   = cr[w];
        const float sNew = (cv < 0.f) ? (float)kwin : cv;  // fill unobserved
        if (lane == 0) outf[i * 4 + cw] = sNew;            // exchange + output

        // raw barrier: LDS ordering only; vmcnt (gumbel prefetch) NOT drained
        asm volatile("s_waitcnt lgkmcnt(0)" ::: "memory");
        __builtin_amdgcn_s_barrier();
        __builtin_amdgcn_sched_barrier(0);

        const float4 ex = outb[i];   // all 3 channels of pixel i
        // shift partial pipeline; prefetch ring slot i+2 (written by shadow
        // pre-barrier(i) -> one FULL step of LDS latency slack before use)
        pdAc = pdAn; pdBc = pdBn;
        if (i + 2 < HW) {
          pdAn = pd[(i + 2) & 3][cw * 128 + lane];
          pdBn = pd[(i + 2) & 3][cw * 128 + 64 + lane];
        }
        sB0 = sA0; sB1 = sA1; sB2 = sA2;
        sA0 = ex.x; sA1 = ex.y; sA2 = ex.z;
        if (t == 0) xp4[h + 2][w + 2] = make_float4(ex.x, ex.y, ex.z, 0.f);
      }
    }
  } else {
    // ================= SHADOW =================
    const int cw = (t >> 6) - 3;
    double wS[3][10], wT[3][10];   // taps 0..9 (rows 0,1), k=lane / lane+64
#pragma unroll
    for (int ci = 0; ci < 3; ++ci)
#pragma unroll
      for (int tap = 0; tap < 10; ++tap) {
        wS[ci][tap] = (double)Wc[(lane * 3 + cw) * 75 + ci * 25 + tap];
        wT[ci][tap] = (double)Wc[((lane + 64) * 3 + cw) * 75 + ci * 25 + tap];
      }

    for (int i = 0; i < HW; ++i) {
      const int j = i + 2;               // produce partial for pixel i+2
      if (j < HW) {
        const int hj = j / WW, wj = j - hj * WW;
        float4 px[10];                   // taps read pixels <= j-10 = i-8
#pragma unroll
        for (int tap = 0; tap < 10; ++tap)
          px[tap] = xp4[hj + tap / 5][wj + tap % 5];
        double pA0 = 0, pA1 = 0, pB0 = 0, pB1 = 0;
#pragma unroll
        for (int tap = 0; tap < 10; ++tap) {
          const float4 v = px[tap];
          if (tap & 1) {
            pA1 = fma((double)v.x, wS[0][tap], pA1);
            pA1 = fma((double)v.y, wS[1][tap], pA1);
            pA1 = fma((double)v.z, wS[2][tap], pA1);
            pB1 = fma((double)v.x, wT[0][tap], pB1);
            pB1 = fma((double)v.y, wT[1][tap], pB1);
            pB1 = fma((double)v.z, wT[2][tap], pB1);
          } else {
            pA0 = fma((double)v.x, wS[0][tap], pA0);
            pA0 = fma((double)v.y, wS[1][tap], pA0);
            pA0 = fma((double)v.z, wS[2][tap], pA0);
            pB0 = fma((double)v.x, wT[0][tap], pB0);
            pB0 = fma((double)v.y, wT[1][tap], pB0);
            pB0 = fma((double)v.z, wT[2][tap], pB0);
          }
        }
        pd[j & 3][cw * 128 + lane]      = pA0 + pA1;   // same tree as verified
        pd[j & 3][cw * 128 + 64 + lane] = pB0 + pB1;
      }
      asm volatile("s_waitcnt lgkmcnt(0)" ::: "memory");
      __builtin_amdgcn_s_barrier();
      __builtin_amdgcn_sched_barrier(0);
    }
  }

  __syncthreads();
  for (int idx = t; idx < CC * HW; idx += 384) {
    const int c = idx / HW, i = idx - c * HW;
    out[n * CC * HW + idx] = outf[i * 4 + c];
  }
}

extern "C" void kernel_launch(void* const* d_in, const int* in_sizes, int n_in,
                              void* d_out, int out_size, void* d_ws, size_t ws_size,
                              hipStream_t stream) {
  const float* cond = (const float*)d_in[0];
  const float* Wc   = (const float*)d_in[1];
  const float* b    = (const float*)d_in[2];
  float* out = (float*)d_out;
  const size_t need = (size_t)NB * HW * KC * sizeof(float);  // 14.2 MB
  if (ws_size >= need) {
    float* gws = (float*)d_ws;
    hipLaunchKernelGGL(gumbel_pre, dim3((NB * HW * KC) / 256), dim3(256), 0,
                       stream, gws);
    hipLaunchKernelGGL((ar_sample<true>), dim3(NB), dim3(384), 0, stream,
                       cond, Wc, b, gws, out);
  } else {
    hipLaunchKernelGGL((ar_sample<false>), dim3(NB), dim3(384), 0, stream,
                       cond, Wc, b, (const float*)nullptr, out);
  }
}

// Round 11
// 155.646 us; speedup vs baseline: 2.6646x; 1.0349x over previous
//
#include <hip/hip_runtime.h>
#include <stdint.h>

#define NB 64
#define CC 3
#define HH 12
#define WW 12
#define HW 144
#define KC 384
#define TINYF 1.17549435e-38f
// VERIFIED round 5/7/10: partitionable RNG (x0^x1) + fp64 conv -> absmax 0.0
#ifndef PARTITIONABLE
#define PARTITIONABLE 1
#endif

__device__ __forceinline__ void tf2x32(uint32_t k0, uint32_t k1,
                                       uint32_t& x0, uint32_t& x1) {
  const uint32_t ks2 = k0 ^ k1 ^ 0x1BD11BDAu;
  x0 += k0; x1 += k1;
#define RND(r) { x0 += x1; x1 = (x1 << (r)) | (x1 >> (32 - (r))); x1 ^= x0; }
  RND(13) RND(15) RND(26) RND(6)   x0 += k1;  x1 += ks2 + 1u;
  RND(17) RND(29) RND(16) RND(24)  x0 += ks2; x1 += k0 + 2u;
  RND(13) RND(15) RND(26) RND(6)   x0 += k0;  x1 += k1 + 3u;
  RND(17) RND(29) RND(16) RND(24)  x0 += k1;  x1 += ks2 + 4u;
  RND(13) RND(15) RND(26) RND(6)   x0 += ks2; x1 += k0 + 5u;
#undef RND
}

__device__ __forceinline__ uint32_t rbits(uint32_t k0, uint32_t k1, uint32_t e) {
#if PARTITIONABLE == 1
  uint32_t x0 = 0u, x1 = e;   // counter (0, e); u32 bits = bits1 ^ bits2
  tf2x32(k0, k1, x0, x1);
  return x0 ^ x1;
#else
  const uint32_t half = (uint32_t)(NB * KC / 2);
  const bool lo = e < half;
  uint32_t x0 = lo ? e : e - half;
  uint32_t x1 = lo ? e + half : e;
  tf2x32(k0, k1, x0, x1);
  return lo ? x0 : x1;
#endif
}

__device__ __forceinline__ float gumbel32(uint32_t k0, uint32_t k1, uint32_t e) {
  const uint32_t bits = rbits(k0, k1, e);
  const float f = __uint_as_float((bits >> 9) | 0x3f800000u) - 1.0f;  // [0,1)
  const float u = fmaxf(TINYF, f + TINYF);
  return (float)(-log(-log((double)u)));
}

// Gumbel precompute, PERMUTED layout: gws[(n*HW+i)*KC + c*128 + k],
// value = gumbel(e = n*KC + k*3 + c)
__global__ __launch_bounds__(256) void gumbel_pre(float* __restrict__ gws) {
  const uint32_t tid = blockIdx.x * 256u + threadIdx.x;
  const uint32_t t  = tid % KC;
  const uint32_t c  = t >> 7, k = t & 127u;
  const uint32_t ni = tid / KC;
  const uint32_t i  = ni % HW;
  const uint32_t n  = ni / HW;
  uint32_t a = 0u, b = i;
  tf2x32(0u, 42u, a, b);
  gws[tid] = gumbel32(a, b, n * KC + k * 3u + c);
}

template<int CTRL>
__device__ __forceinline__ float dpp_max_step(float v) {
  const int o = __builtin_amdgcn_update_dpp(0xFF800000, __float_as_int(v),
                                            CTRL, 0xF, 0xF, false); // old=-inf
  return fmaxf(v, __int_as_float(o));
}
__device__ __forceinline__ float wave_max_bcast(float v) {
  v = dpp_max_step<0x111>(v);  // row_shr:1
  v = dpp_max_step<0x112>(v);  // row_shr:2
  v = dpp_max_step<0x114>(v);  // row_shr:4
  v = dpp_max_step<0x118>(v);  // row_shr:8
  v = dpp_max_step<0x142>(v);  // row_bcast:15
  v = dpp_max_step<0x143>(v);  // row_bcast:31
  return __int_as_float(__builtin_amdgcn_readlane(__float_as_int(v), 63));
}

#define REGION_BARRIER() do {                               \
    asm volatile("s_waitcnt lgkmcnt(0)" ::: "memory");      \
    __builtin_amdgcn_s_barrier();                           \
    __builtin_amdgcn_sched_barrier(0);                      \
  } while (0)

// 7 waves: wave 0 = SAMPLER (all 384 logits: lane holds (c,k=lane),(c,k=lane+64)
// for c=0..2; in-register sample feedback, no LDS exchange on critical path).
// waves 1-6 = SHADOW (one output/lane; rows-0/1 10-tap partial for pixel r+2,
// px double-buffered one region ahead, published into 4-slot fp64 ring).
template<bool PRE>
__global__ __launch_bounds__(448, 1) void ar_sample(
    const float* __restrict__ cond,   // [N,C,H,W]
    const float* __restrict__ Wc,     // [K*C, C, 5, 5]
    const float* __restrict__ bias,   // [K*C]
    const float* __restrict__ gws,    // [N,HW,C,K] gumbels (PRE)
    float* __restrict__ out)          // [N,C,H,W]
{
  __shared__ float4   xp4[HH + 2][WW + 4];  // padded image (= output image)
  __shared__ float    cndl[CC * HW];
  __shared__ double   pd[4][KC];            // partial ring, slot = pixel&3
  __shared__ uint32_t k0s[HW], k1s[HW];     // !PRE only

  const int n = blockIdx.x, t = threadIdx.x, lane = t & 63;

  for (int idx = t; idx < (HH + 2) * (WW + 4); idx += 448)
    ((float4*)xp4)[idx] = make_float4(0.f, 0.f, 0.f, 0.f);
  for (int idx = t; idx < CC * HW; idx += 448)
    cndl[idx] = cond[n * CC * HW + idx];
  for (int idx = t; idx < 4 * KC; idx += 448)
    ((double*)pd)[idx] = 0.0;               // pixels 0..2 partials = 0
  if (!PRE && t < HW) {
    uint32_t a = 0u, b = (uint32_t)t;
    tf2x32(0u, 42u, a, b);
    k0s[t] = a; k1s[t] = b;
  }
  __syncthreads();

  if (t < 64) {
    // ================= SAMPLER (wave 0) =================
    double w11[6][3], w10[6][3];   // completion weights, o = c*2 + j (j: k half)
    float  bs[6];
#pragma unroll
    for (int c = 0; c < 3; ++c)
#pragma unroll
      for (int j = 0; j < 2; ++j) {
        const int o = c * 2 + j, k = lane + j * 64;
#pragma unroll
        for (int ci = 0; ci < 3; ++ci) {
          w11[o][ci] = (double)Wc[(k * 3 + c) * 75 + ci * 25 + 11];
          w10[o][ci] = (double)Wc[(k * 3 + c) * 75 + ci * 25 + 10];
        }
        bs[o] = bias[k * 3 + c];
      }
    float gum[6][4];               // 4 rotating slots, prefetch 3 ahead
    if (PRE) {
#pragma unroll
      for (int p = 0; p < 3; ++p)
#pragma unroll
        for (int c = 0; c < 3; ++c)
#pragma unroll
          for (int j = 0; j < 2; ++j)
            gum[c * 2 + j][p] = gws[(n * HW + p) * KC + c * 128 + lane + j * 64];
    }
    float cnd_cur[3], cnd_nxt[3];
#pragma unroll
    for (int c = 0; c < 3; ++c) cnd_cur[c] = cndl[c * HW + 0];
    double pdc[6] = {0, 0, 0, 0, 0, 0}, pdn[6];
    double e11[6], e10[6];         // consumed only under w>=1 / w>=2 guards
    float sA0 = 0.f, sA1 = 0.f, sA2 = 0.f;   // sample i-1
    __builtin_amdgcn_s_setprio(1);

    for (int h = 0; h < HH; ++h) {
#pragma unroll
      for (int w = 0; w < WW; ++w) {
        const int i = h * WW + w;
        // ring reads: partial(pixel i+1), slot (i+1)&3 == (w+1)&3 (written by
        // shadow in region i-1, completed at barrier(i-1)). One region slack.
#pragma unroll
        for (int c = 0; c < 3; ++c)
#pragma unroll
          for (int j = 0; j < 2; ++j)
            pdn[c * 2 + j] = pd[(w + 1) & 3][c * 128 + lane + j * 64];
        {
          const int i1 = (i + 1 < HW) ? i + 1 : HW - 1;
#pragma unroll
          for (int c = 0; c < 3; ++c) cnd_nxt[c] = cndl[c * HW + i1];
        }
        if (PRE) {                 // gumbels for step i+3, slot (w+3)&3
          const int i3 = (i + 3 < HW) ? i + 3 : HW - 1;
#pragma unroll
          for (int c = 0; c < 3; ++c)
#pragma unroll
            for (int j = 0; j < 2; ++j)
              gum[c * 2 + j][(w + 3) & 3] =
                  gws[(n * HW + i3) * KC + c * 128 + lane + j * 64];
        }
        // logits: verified order ((pdc + e11) + e10), f32 bias then gumbel
        float v[6];
#pragma unroll
        for (int o = 0; o < 6; ++o) {
          double tA = pdc[o];
          if (w >= 1) tA += e11[o];
          if (w >= 2) tA += e10[o];
          float g;
          if (PRE) g = gum[o][w & 3];
          else {
            const int c = o >> 1, k = lane + (o & 1) * 64;
            g = gumbel32(k0s[i], k1s[i], n * KC + k * 3 + c);
          }
          v[o] = ((float)tA + bs[o]) + g;
        }
        // per-channel first-max-wins argmax (3 interleaved DPP chains)
        float sN[3];
#pragma unroll
        for (int c = 0; c < 3; ++c) {
          const float vm   = fmaxf(v[c * 2], v[c * 2 + 1]);
          const float smax = wave_max_bcast(vm);
          const unsigned long long aM = __ballot(v[c * 2] == smax);
          const unsigned long long bM = __ballot(v[c * 2 + 1] == smax);
          const int kwin = aM ? (int)__builtin_ctzll(aM)
                              : (int)__builtin_ctzll(bM) + 64;
          sN[c] = (cnd_cur[c] < 0.f) ? (float)kwin : cnd_cur[c];
        }
        if (lane == 0) xp4[h + 2][w + 2] = make_float4(sN[0], sN[1], sN[2], 0.f);
        // completion terms for pixel i+1: e11 <- sample i (sN), e10 <- sample
        // i-1 (sA). Same fp64 trees as verified -> bit-identical.
#pragma unroll
        for (int o = 0; o < 6; ++o) {
          e11[o] = ((double)sN[0] * w11[o][0] + (double)sN[1] * w11[o][1])
                 +  (double)sN[2] * w11[o][2];
          e10[o] = ((double)sA0 * w10[o][0] + (double)sA1 * w10[o][1])
                 +  (double)sA2 * w10[o][2];
        }
        sA0 = sN[0]; sA1 = sN[1]; sA2 = sN[2];
        REGION_BARRIER();
#pragma unroll
        for (int o = 0; o < 6; ++o) pdc[o] = pdn[o];
#pragma unroll
        for (int c = 0; c < 3; ++c) cnd_cur[c] = cnd_nxt[c];
      }
    }
  } else {
    // ================= SHADOW (waves 1-6) =================
    const int o = t - 64;          // 0..383 = c*128 + k
    const int c = o >> 7, k = o & 127;
    double wsd[3][10];
#pragma unroll
    for (int ci = 0; ci < 3; ++ci)
#pragma unroll
      for (int tap = 0; tap < 10; ++tap)
        wsd[ci][tap] = (double)Wc[(k * 3 + c) * 75 + ci * 25 + tap];

    float4 pxA[10], pxB[10];       // double-buffered tap reads

#define SHADOW_REGION(r, pxC, pxF) {                                         \
      const int j2 = ((r) + 3 < HW) ? (r) + 3 : HW - 1;                      \
      const int hj = j2 / WW, wj = j2 - hj * WW;                             \
      _Pragma("unroll")                                                      \
      for (int tap = 0; tap < 10; ++tap)                                     \
        pxF[tap] = xp4[hj + tap / 5][wj + tap % 5];                          \
      if ((r) >= 1 && (r) <= HW - 3) {   /* write pixel j=r+2 in [3,143] */  \
        double p0 = 0.0, p1 = 0.0;                                           \
        _Pragma("unroll")                                                    \
        for (int tap = 0; tap < 10; ++tap) {                                 \
          const float4 vv = pxC[tap];                                        \
          if (tap & 1) {                                                     \
            p1 = fma((double)vv.x, wsd[0][tap], p1);                         \
            p1 = fma((double)vv.y, wsd[1][tap], p1);                         \
            p1 = fma((double)vv.z, wsd[2][tap], p1);                         \
          } else {                                                           \
            p0 = fma((double)vv.x, wsd[0][tap], p0);                         \
            p0 = fma((double)vv.y, wsd[1][tap], p0);                         \
            p0 = fma((double)vv.z, wsd[2][tap], p0);                         \
          }                                                                  \
        }                                                                    \
        pd[((r) + 2) & 3][o] = p0 + p1;   /* verified even+odd tree */       \
      }                                                                      \
      REGION_BARRIER();                                                      \
    }

    for (int r = 0; r < HW; r += 2) {
      SHADOW_REGION(r,     pxA, pxB)   // consume pxA (read in r-1), fill pxB
      SHADOW_REGION(r + 1, pxB, pxA)
    }
#undef SHADOW_REGION
  }

  __syncthreads();
  for (int idx = t; idx < CC * HW; idx += 448) {
    const int c = idx / HW, i = idx - c * HW;
    const int h = i / WW, w = i - h * WW;
    out[n * CC * HW + idx] = ((const float*)&xp4[h + 2][w + 2])[c];
  }
}

extern "C" void kernel_launch(void* const* d_in, const int* in_sizes, int n_in,
                              void* d_out, int out_size, void* d_ws, size_t ws_size,
                              hipStream_t stream) {
  const float* cond = (const float*)d_in[0];
  const float* Wc   = (const float*)d_in[1];
  const float* b    = (const float*)d_in[2];
  float* out = (float*)d_out;
  const size_t need = (size_t)NB * HW * KC * sizeof(float);  // 14.2 MB
  if (ws_size >= need) {
    float* gws = (float*)d_ws;
    hipLaunchKernelGGL(gumbel_pre, dim3((NB * HW * KC) / 256), dim3(256), 0,
                       stream, gws);
    hipLaunchKernelGGL((ar_sample<true>), dim3(NB), dim3(448), 0, stream,
                       cond, Wc, b, gws, out);
  } else {
    hipLaunchKernelGGL((ar_sample<false>), dim3(NB), dim3(448), 0, stream,
                       cond, Wc, b, (const float*)nullptr, out);
  }
}